// Round 3
// baseline (20496.739 us; speedup 1.0000x reference)
//
#include <hip/hip_runtime.h>
#include <hip/hip_bf16.h>

typedef __attribute__((ext_vector_type(8))) short bf16x8;
typedef __attribute__((ext_vector_type(4))) float f32x4;
typedef __attribute__((ext_vector_type(16))) float f32x16;
typedef unsigned long long u64;

#define S_LEN 2048
#define BATCH 64
#define IDIM 256
#define HDIM 512
#define KDIM 768
#define ODIM 512
#define LDK 772   // comb LDS row stride (shorts): 2-way bank alias (free), 8B-aligned rows
#define LDH 520   // consumer h LDS row stride (shorts)
#define NPROD 32
#define NCONS 64
#define NBLK (NPROD + NCONS)
#define FLAG_STRIDE 16  // ints -> 64B per producer flag slot

// producer LDS map (bytes)
#define OFF_PRE 49408    // comb = 32*LDK*2
#define OFF_BIAS 83200   // pre = 2*32*132*4 = 33792
#define OFF_HBUF 83712   // bias 128*4
#define SMEM_BYTES 85760 // + hbuf 32*32*2 ; consumer needs 64*LDH*2 = 66560 <= this

__device__ __forceinline__ unsigned short f2b(float f) {
  __hip_bfloat16 h = __float2bfloat16(f);
  return __builtin_bit_cast(unsigned short, h);
}
__device__ __forceinline__ float sigmoidf_(float x) { return 1.0f / (1.0f + __expf(-x)); }
__device__ __forceinline__ float tanhf_(float x) { return 1.0f - 2.0f / (1.0f + __expf(2.0f * x)); }

__device__ __forceinline__ bf16x8 cvt8(float4 v0, float4 v1) {
  bf16x8 b;
  b[0] = (short)f2b(v0.x); b[1] = (short)f2b(v0.y);
  b[2] = (short)f2b(v0.z); b[3] = (short)f2b(v0.w);
  b[4] = (short)f2b(v1.x); b[5] = (short)f2b(v1.y);
  b[6] = (short)f2b(v1.z); b[7] = (short)f2b(v1.w);
  return b;
}

// LLC-coherent (sc1) accesses: no L2 writeback/invalidate anywhere.
__device__ __forceinline__ u64 llc_load_u64(const u64* p) {
  return __hip_atomic_load(p, __ATOMIC_RELAXED, __HIP_MEMORY_SCOPE_AGENT);
}
__device__ __forceinline__ void llc_store_u64(u64* p, u64 v) {
  __hip_atomic_store(p, v, __ATOMIC_RELAXED, __HIP_MEMORY_SCOPE_AGENT);
}
__device__ __forceinline__ int llc_load_i32(const int* p) {
  return __hip_atomic_load(p, __ATOMIC_RELAXED, __HIP_MEMORY_SCOPE_AGENT);
}

__global__ void lstm_init(const float* __restrict__ wh2o,
                          __hip_bfloat16* __restrict__ wh2o_bf,
                          __hip_bfloat16* __restrict__ h_all,
                          int* __restrict__ flags) {
  int idx = blockIdx.x * 256 + threadIdx.x;
  if (idx < ODIM * HDIM) wh2o_bf[idx] = __float2bfloat16(wh2o[idx]);
  if (idx < BATCH * HDIM) h_all[idx] = __float2bfloat16(0.0f);  // slot 0 = h0 = 0
  if (idx < 4096) flags[idx] = 0;
}

__global__ __launch_bounds__(512) void lstm_persist(
    const float* __restrict__ x,
    const float* __restrict__ Wi, const float* __restrict__ bi,
    const float* __restrict__ Wf, const float* __restrict__ bfp,
    const float* __restrict__ Wg, const float* __restrict__ bgp,
    const float* __restrict__ Wo, const float* __restrict__ bop,
    const __hip_bfloat16* __restrict__ wh2o_bf, const float* __restrict__ bh2o,
    __hip_bfloat16* __restrict__ h_all, int* __restrict__ flags,
    float* __restrict__ out) {
  extern __shared__ char smem[];
  const int tid = threadIdx.x;
  const int lane = tid & 63;
  const int wave = tid >> 6;

  if (blockIdx.x < NPROD) {
    // ===== producer: 32 h-cols x 32 batch rows; 8 waves = 4 gates x 2 K-halves =====
    const int p = blockIdx.x;
    const int hg = p >> 1;  // 16 groups of 32 h-cols
    const int bgr = p & 1;  // batch half
    short* comb = (short*)smem;               // [32][LDK] bf16: x(256) | h(512)
    float* pre = (float*)(smem + OFF_PRE);    // [2][32][132] partial preacts
    float* blds = (float*)(smem + OFF_BIAS);  // [128]
    short* hbuf = (short*)(smem + OFF_HBUF);  // [32][32]

    const int ct = wave & 3;   // gate / col-tile
    const int kh = wave >> 2;  // K-half
    const int bl = lane & 31;
    const int ksub = (lane >> 5) * 8;

    // --- prologue: weight fragments straight from global fp32 -> registers ---
    const float* wsrc = (ct == 0) ? Wi : (ct == 1) ? Wf : (ct == 2) ? Wg : Wo;
    const float* wrow = wsrc + (size_t)(hg * 32 + bl) * KDIM;
    bf16x8 bfx[8], bfh[16];
#pragma unroll
    for (int kk = 0; kk < 8; ++kk) {
      int k0 = kh * 128 + kk * 16 + ksub;
      bfx[kk] = cvt8(*(const float4*)(wrow + k0), *(const float4*)(wrow + k0 + 4));
    }
#pragma unroll
    for (int kk = 0; kk < 16; ++kk) {
      int k0 = IDIM + kh * 256 + kk * 16 + ksub;
      bfh[kk] = cvt8(*(const float4*)(wrow + k0), *(const float4*)(wrow + k0 + 4));
    }
    if (tid < 128) {
      int g = tid >> 5;
      const float* bsrc = (g == 0) ? bi : (g == 1) ? bfp : (g == 2) ? bgp : bop;
      blds[tid] = bsrc[hg * 32 + (tid & 31)];
    }

    float cst0 = 0.0f, cst1 = 0.0f;  // c state: 2 (row,h) pairs per thread

    auto stage_x = [&](int t) {
      const float4* xs = (const float4*)(x + ((size_t)t * BATCH + bgr * 32) * IDIM);
      for (int i = tid; i < 2048; i += 512) {
        int r = i >> 6, k4 = i & 63;
        float4 v = xs[r * 64 + k4];
        ushort4 u;
        u.x = f2b(v.x); u.y = f2b(v.y); u.z = f2b(v.z); u.w = f2b(v.w);
        *(ushort4*)&comb[r * LDK + k4 * 4] = u;
      }
    };
    auto stage_h = [&](int slot) {
      const u64* hs = (const u64*)h_all + ((size_t)slot * BATCH + bgr * 32) * (HDIM / 4);
      for (int i = tid; i < 4096; i += 512) {
        int r = i >> 7, cc = i & 127;
        u64 v = llc_load_u64(hs + r * 128 + cc);
        *(u64*)&comb[r * LDK + IDIM + cc * 4] = v;
      }
    };

    const short* arow = &comb[bl * LDK];

    // t=0 x-part prefetch
    stage_x(0);
    __syncthreads();
    f32x16 acc = {};
#pragma unroll
    for (int kk = 0; kk < 8; ++kk) {
      bf16x8 a = *(const bf16x8*)(arow + kh * 128 + kk * 16 + ksub);
      acc = __builtin_amdgcn_mfma_f32_32x32x16_bf16(a, bfx[kk], acc, 0, 0, 0);
    }

    for (int t = 0; t < S_LEN; ++t) {
      // wait until all producers have published h_t (t=0: trivially true)
      if (wave == 0) {
        for (;;) {
          int v = (lane < NPROD) ? llc_load_i32(flags + lane * FLAG_STRIDE) : 0x7fffffff;
          if (__all(v >= t)) break;
        }
      }
      __syncthreads();
      stage_h(t);
      __syncthreads();
      // h-part GEMM (K=512 split over kh)
#pragma unroll
      for (int kk = 0; kk < 16; ++kk) {
        bf16x8 a = *(const bf16x8*)(arow + IDIM + kh * 256 + kk * 16 + ksub);
        acc = __builtin_amdgcn_mfma_f32_32x32x16_bf16(a, bfh[kk], acc, 0, 0, 0);
      }
#pragma unroll
      for (int r = 0; r < 16; ++r) {
        int row = (r & 3) + 8 * (r >> 2) + 4 * (lane >> 5);
        pre[(kh * 32 + row) * 132 + ct * 32 + bl] = acc[r];
      }
      __syncthreads();
      // gates + state update: 2 (row,h) pairs per thread
#pragma unroll
      for (int pp = 0; pp < 2; ++pp) {
        int idx = tid * 2 + pp;
        int row = idx >> 5, hl = idx & 31;
        const float* p0 = &pre[row * 132];
        const float* p1 = &pre[(32 + row) * 132];
        float pi = blds[hl] + p0[hl] + p1[hl];
        float pf = blds[32 + hl] + p0[32 + hl] + p1[32 + hl];
        float pg = blds[64 + hl] + p0[64 + hl] + p1[64 + hl];
        float po = blds[96 + hl] + p0[96 + hl] + p1[96 + hl];
        float ig = sigmoidf_(pi), fg = sigmoidf_(pf), gv = tanhf_(pg), og = sigmoidf_(po);
        float& cs = pp ? cst1 : cst0;
        cs = fg * cs + ig * gv;
        hbuf[row * 32 + hl] = (short)f2b(og * tanhf_(cs));
      }
      __syncthreads();
      // publish h_{t+1}: sc1 write-through to LLC, drain, then own-slot flag
      if (tid < 256) {
        int r = tid >> 3, c8 = tid & 7;
        u64 v = *(const u64*)&hbuf[r * 32 + c8 * 4];
        llc_store_u64((u64*)h_all + ((size_t)(t + 1) * BATCH + bgr * 32 + r) * (HDIM / 4) +
                          hg * 8 + c8,
                      v);
      }
      asm volatile("s_waitcnt vmcnt(0)" ::: "memory");
      __syncthreads();
      if (tid == 0)
        __hip_atomic_store(flags + p * FLAG_STRIDE, t + 1, __ATOMIC_RELAXED,
                           __HIP_MEMORY_SCOPE_AGENT);
      // x-part prefetch for t+1 during the wait window
      if (t + 1 < S_LEN) {
        stage_x(t + 1);
        __syncthreads();
        f32x16 z = {};
        acc = z;
#pragma unroll
        for (int kk = 0; kk < 8; ++kk) {
          bf16x8 a = *(const bf16x8*)(arow + kh * 128 + kk * 16 + ksub);
          acc = __builtin_amdgcn_mfma_f32_32x32x16_bf16(a, bfx[kk], acc, 0, 0, 0);
        }
      }
    }
  } else {
    // ===== consumer: 512 threads; all stage, waves 0-3 compute =====
    const int q = blockIdx.x - NPROD;
    short* hlds = (short*)smem;  // [64][LDH]
    for (int t = q; t < S_LEN; t += NCONS) {
      if (wave == 0) {
        for (;;) {
          int v = (lane < NPROD) ? llc_load_i32(flags + lane * FLAG_STRIDE) : 0x7fffffff;
          if (__all(v >= t + 1)) break;
          __builtin_amdgcn_s_sleep(2);
        }
      }
      __syncthreads();
      const u64* hs = (const u64*)h_all + (size_t)(t + 1) * BATCH * (HDIM / 4);
      for (int i = tid; i < 8192; i += 512) {
        int r = i >> 7, cc = i & 127;
        *(u64*)&hlds[r * LDH + cc * 4] = llc_load_u64(hs + i);
      }
      __syncthreads();
      f32x4 acc[32];
      if (wave < 4) {
        const int r0 = wave * 16;
        const short* abase = &hlds[(r0 + (lane & 15)) * LDH + (lane >> 4) * 8];
        const short* bbase = (const short*)wh2o_bf + (size_t)(lane & 15) * HDIM + (lane >> 4) * 8;
        f32x4 zero = {0.f, 0.f, 0.f, 0.f};
#pragma unroll
        for (int n = 0; n < 32; ++n) acc[n] = zero;
        for (int kk = 0; kk < 16; ++kk) {
          bf16x8 a = *(const bf16x8*)(abase + kk * 32);
#pragma unroll
          for (int n = 0; n < 32; ++n) {
            bf16x8 b = *(const bf16x8*)(bbase + (size_t)n * 16 * HDIM + kk * 32);
            acc[n] = __builtin_amdgcn_mfma_f32_16x16x32_bf16(a, b, acc[n], 0, 0, 0);
          }
        }
      }
      __syncthreads();  // hlds consumption complete
      if (wave < 4) {
        const int r0 = wave * 16;
        float mx[4] = {-3.0e38f, -3.0e38f, -3.0e38f, -3.0e38f};
#pragma unroll
        for (int n = 0; n < 32; ++n) {
          float bn = bh2o[n * 16 + (lane & 15)];
#pragma unroll
          for (int j = 0; j < 4; ++j) {
            acc[n][j] += bn;
            mx[j] = fmaxf(mx[j], acc[n][j]);
          }
        }
#pragma unroll
        for (int j = 0; j < 4; ++j) {
          mx[j] = fmaxf(mx[j], __shfl_xor(mx[j], 1));
          mx[j] = fmaxf(mx[j], __shfl_xor(mx[j], 2));
          mx[j] = fmaxf(mx[j], __shfl_xor(mx[j], 4));
          mx[j] = fmaxf(mx[j], __shfl_xor(mx[j], 8));
        }
        float sm[4] = {0.f, 0.f, 0.f, 0.f};
#pragma unroll
        for (int n = 0; n < 32; ++n) {
#pragma unroll
          for (int j = 0; j < 4; ++j) sm[j] += __expf(acc[n][j] - mx[j]);
        }
#pragma unroll
        for (int j = 0; j < 4; ++j) {
          sm[j] += __shfl_xor(sm[j], 1);
          sm[j] += __shfl_xor(sm[j], 2);
          sm[j] += __shfl_xor(sm[j], 4);
          sm[j] += __shfl_xor(sm[j], 8);
        }
        float ls[4];
#pragma unroll
        for (int j = 0; j < 4; ++j) ls[j] = mx[j] + __logf(sm[j]);
        float* ob = out + (size_t)t * BATCH * ODIM;
#pragma unroll
        for (int n = 0; n < 32; ++n) {
#pragma unroll
          for (int j = 0; j < 4; ++j) {
            int row = r0 + (lane >> 4) * 4 + j;
            ob[(size_t)row * ODIM + n * 16 + (lane & 15)] = acc[n][j] - ls[j];
          }
        }
      }
    }
  }
}

extern "C" void kernel_launch(void* const* d_in, const int* in_sizes, int n_in,
                              void* d_out, int out_size, void* d_ws, size_t ws_size,
                              hipStream_t stream) {
  const float* x = (const float*)d_in[0];
  const float* Wi = (const float*)d_in[1];
  const float* bi = (const float*)d_in[2];
  const float* Wf = (const float*)d_in[3];
  const float* bf = (const float*)d_in[4];
  const float* Wg = (const float*)d_in[5];
  const float* bg = (const float*)d_in[6];
  const float* Wo = (const float*)d_in[7];
  const float* bo = (const float*)d_in[8];
  const float* Wh2o = (const float*)d_in[9];
  const float* bh2o = (const float*)d_in[10];

  char* ws = (char*)d_ws;
  int* flags = (int*)ws;
  __hip_bfloat16* h_all = (__hip_bfloat16*)(ws + 16384);
  size_t h_all_bytes = (size_t)(S_LEN + 1) * BATCH * HDIM * 2;
  __hip_bfloat16* wh2o_bf = (__hip_bfloat16*)(ws + 16384 + h_all_bytes);
  size_t needed = 16384 + h_all_bytes + (size_t)ODIM * HDIM * 2;
  if (ws_size < needed || n_in < 11) return;

  hipFuncSetAttribute((const void*)lstm_persist,
                      hipFuncAttributeMaxDynamicSharedMemorySize, SMEM_BYTES);

  lstm_init<<<1024, 256, 0, stream>>>(Wh2o, wh2o_bf, h_all, flags);
  lstm_persist<<<NBLK, 512, SMEM_BYTES, stream>>>(x, Wi, bi, Wf, bf, Wg, bg, Wo, bo,
                                                  wh2o_bf, bh2o, h_all, flags,
                                                  (float*)d_out);
}

// Round 4
// 19888.373 us; speedup vs baseline: 1.0306x; 1.0306x over previous
//
#include <hip/hip_runtime.h>
#include <hip/hip_bf16.h>

typedef __attribute__((ext_vector_type(8))) short bf16x8;
typedef __attribute__((ext_vector_type(4))) float f32x4;
typedef __attribute__((ext_vector_type(16))) float f32x16;
typedef unsigned long long u64;
typedef unsigned int u32t;

#define S_LEN 2048
#define BATCH 64
#define IDIM 256
#define HDIM 512
#define KDIM 768
#define ODIM 512
#define LDX 264   // x LDS row stride (shorts): 528B rows, 16B-aligned, mild bank spread
#define LDH 520   // consumer h LDS row stride (shorts)
#define NPROD 32
#define NCONS 64
#define NBLK (NPROD + NCONS)
#define REP_STRIDE 64  // ints per flag replica (256B); 8 replicas

// producer LDS map (bytes): xlds [32][LDX]*2B = 16896 ; pre [2][32][132]*4B = 33792 ; bias 512B
#define OFF_PRE 16896
#define OFF_BIAS 50688
#define SMEM_BYTES 66560  // consumer hlds [64][LDH]*2B = 66560 dominates

__device__ __forceinline__ unsigned short f2b(float f) {
  __hip_bfloat16 h = __float2bfloat16(f);
  return __builtin_bit_cast(unsigned short, h);
}
__device__ __forceinline__ float sigmoidf_(float x) { return 1.0f / (1.0f + __expf(-x)); }
__device__ __forceinline__ float tanhf_(float x) { return 1.0f - 2.0f / (1.0f + __expf(2.0f * x)); }

__device__ __forceinline__ bf16x8 cvt8(float4 v0, float4 v1) {
  bf16x8 b;
  b[0] = (short)f2b(v0.x); b[1] = (short)f2b(v0.y);
  b[2] = (short)f2b(v0.z); b[3] = (short)f2b(v0.w);
  b[4] = (short)f2b(v1.x); b[5] = (short)f2b(v1.y);
  b[6] = (short)f2b(v1.z); b[7] = (short)f2b(v1.w);
  return b;
}

// LLC-coherent (sc1) accesses: no L2 writeback/invalidate anywhere.
__device__ __forceinline__ u64 llc_load_u64(const u64* p) {
  return __hip_atomic_load(p, __ATOMIC_RELAXED, __HIP_MEMORY_SCOPE_AGENT);
}
__device__ __forceinline__ void llc_store_u32(u32t* p, u32t v) {
  __hip_atomic_store(p, v, __ATOMIC_RELAXED, __HIP_MEMORY_SCOPE_AGENT);
}
__device__ __forceinline__ void llc_store_i32(int* p, int v) {
  __hip_atomic_store(p, v, __ATOMIC_RELAXED, __HIP_MEMORY_SCOPE_AGENT);
}
__device__ __forceinline__ int llc_load_i32(const int* p) {
  return __hip_atomic_load(p, __ATOMIC_RELAXED, __HIP_MEMORY_SCOPE_AGENT);
}

union HFrag {
  u64 q[2];
  bf16x8 v;
};

__global__ void lstm_init(const float* __restrict__ wh2o,
                          __hip_bfloat16* __restrict__ wh2o_bf,
                          __hip_bfloat16* __restrict__ h_all,
                          int* __restrict__ flags) {
  int idx = blockIdx.x * 256 + threadIdx.x;
  if (idx < ODIM * HDIM) wh2o_bf[idx] = __float2bfloat16(wh2o[idx]);
  if (idx < BATCH * HDIM) h_all[idx] = __float2bfloat16(0.0f);  // slot 0 = h0 = 0
  if (idx < 4096) flags[idx] = 0;
}

__global__ __launch_bounds__(512) void lstm_persist(
    const float* __restrict__ x,
    const float* __restrict__ Wi, const float* __restrict__ bi,
    const float* __restrict__ Wf, const float* __restrict__ bfp,
    const float* __restrict__ Wg, const float* __restrict__ bgp,
    const float* __restrict__ Wo, const float* __restrict__ bop,
    const __hip_bfloat16* __restrict__ wh2o_bf, const float* __restrict__ bh2o,
    __hip_bfloat16* __restrict__ h_all, int* __restrict__ flags,
    float* __restrict__ out) {
  extern __shared__ char smem[];
  const int tid = threadIdx.x;
  const int lane = tid & 63;
  const int wave = tid >> 6;

  if (blockIdx.x < NPROD) {
    // ===== producer: 32 h-cols x 32 batch rows; 8 waves = 4 gates x 2 K-halves =====
    const int p = blockIdx.x;
    const int hg = p >> 1;  // 16 groups of 32 h-cols
    const int bgr = p & 1;  // batch half
    short* xlds = (short*)smem;               // [32][LDX] bf16 x slab
    float* pre = (float*)(smem + OFF_PRE);    // [2][32][132] partial preacts
    float* blds = (float*)(smem + OFF_BIAS);  // [128]
    int* rep = flags + (p & 7) * REP_STRIDE;  // this block's poll replica

    const int ct = wave & 3;   // gate
    const int kh = wave >> 2;  // K-half
    const int bl = lane & 31;
    const int hi = lane >> 5;
    const int ksub = hi * 8;

    // --- prologue: weight fragments straight from global fp32 -> registers ---
    const float* wsrc = (ct == 0) ? Wi : (ct == 1) ? Wf : (ct == 2) ? Wg : Wo;
    const float* wrow = wsrc + (size_t)(hg * 32 + bl) * KDIM;
    bf16x8 bfx[8], bfh[16];
#pragma unroll
    for (int kk = 0; kk < 8; ++kk) {
      int k0 = kh * 128 + kk * 16 + ksub;
      bfx[kk] = cvt8(*(const float4*)(wrow + k0), *(const float4*)(wrow + k0 + 4));
    }
#pragma unroll
    for (int kk = 0; kk < 16; ++kk) {
      int k0 = IDIM + kh * 256 + kk * 16 + ksub;
      bfh[kk] = cvt8(*(const float4*)(wrow + k0), *(const float4*)(wrow + k0 + 4));
    }
    if (tid < 128) {
      int g = tid >> 5;
      const float* bsrc = (g == 0) ? bi : (g == 1) ? bfp : (g == 2) ? bgp : bop;
      blds[tid] = bsrc[hg * 32 + (tid & 31)];
    }

    float cst0 = 0.0f, cst1 = 0.0f;  // c state: 2 (row,h) pairs per thread
    const int grow = tid >> 4;       // gate-phase row 0..31
    const int ghl = (tid << 1) & 31; // gate-phase h pair (even)

    float4 rx[4];  // x(t+2) in-flight registers
    auto ldx = [&](int t) {
      const float4* xs = (const float4*)(x + ((size_t)t * BATCH + bgr * 32) * IDIM);
#pragma unroll
      for (int j = 0; j < 4; ++j) rx[j] = xs[tid + j * 512];
    };
    auto stx = [&]() {  // regs -> LDS slab (bf16)
#pragma unroll
      for (int j = 0; j < 4; ++j) {
        int i = tid + j * 512;
        int r = i >> 6, k4 = i & 63;
        float4 v = rx[j];
        ushort4 u;
        u.x = f2b(v.x); u.y = f2b(v.y); u.z = f2b(v.z); u.w = f2b(v.w);
        *(ushort4*)&xlds[r * LDX + k4 * 4] = u;
      }
    };

    const short* axrow = &xlds[bl * LDX];
    f32x16 acc;

    // bootstrap: x(0) -> LDS -> acc ; x(1) -> regs
    ldx(0);
    stx();
    __syncthreads();
    {
      f32x16 z = {};
      acc = z;
#pragma unroll
      for (int kk = 0; kk < 8; ++kk) {
        bf16x8 a = *(const bf16x8*)(axrow + kh * 128 + kk * 16 + ksub);
        acc = __builtin_amdgcn_mfma_f32_32x32x16_bf16(a, bfx[kk], acc, 0, 0, 0);
      }
    }
    ldx(1);

    for (int t = 0; t < S_LEN; ++t) {
      // --- all waves poll own replica: all producers published h_t ---
      for (;;) {
        int v = (lane < NPROD) ? llc_load_i32(rep + lane) : 0x7fffffff;
        if (__all(v >= t)) break;
      }
      asm volatile("" ::: "memory");
      // --- h-part GEMM: A-fragments loaded straight from LLC, no LDS ---
      {
        const u64* hq = (const u64*)h_all +
                        ((size_t)t * BATCH + bgr * 32 + bl) * (HDIM / 4) + kh * 64 + hi * 2;
#pragma unroll
        for (int kk = 0; kk < 16; ++kk) {
          HFrag u;
          u.q[0] = llc_load_u64(hq + kk * 4);
          u.q[1] = llc_load_u64(hq + kk * 4 + 1);
          acc = __builtin_amdgcn_mfma_f32_32x32x16_bf16(u.v, bfh[kk], acc, 0, 0, 0);
        }
      }
      // --- exchange preacts across waves ---
#pragma unroll
      for (int r = 0; r < 16; ++r) {
        int row = (r & 3) + 8 * (r >> 2) + 4 * hi;
        pre[(kh * 32 + row) * 132 + ct * 32 + bl] = acc[r];
      }
      __syncthreads();
      // --- gates + state update: 2 adjacent (row,h) pairs per thread ---
      {
        const float* p0 = &pre[grow * 132];
        const float* p1 = &pre[(32 + grow) * 132];
        float2 ai = *(const float2*)(p0 + ghl);
        float2 bi2 = *(const float2*)(p1 + ghl);
        float2 af = *(const float2*)(p0 + 32 + ghl);
        float2 bf2 = *(const float2*)(p1 + 32 + ghl);
        float2 ag = *(const float2*)(p0 + 64 + ghl);
        float2 bg2 = *(const float2*)(p1 + 64 + ghl);
        float2 ao = *(const float2*)(p0 + 96 + ghl);
        float2 bo2 = *(const float2*)(p1 + 96 + ghl);
        float2 ci = *(const float2*)&blds[ghl];
        float2 cf = *(const float2*)&blds[32 + ghl];
        float2 cg = *(const float2*)&blds[64 + ghl];
        float2 co = *(const float2*)&blds[96 + ghl];
        float i0 = sigmoidf_(ci.x + ai.x + bi2.x), i1 = sigmoidf_(ci.y + ai.y + bi2.y);
        float f0 = sigmoidf_(cf.x + af.x + bf2.x), f1 = sigmoidf_(cf.y + af.y + bf2.y);
        float g0 = tanhf_(cg.x + ag.x + bg2.x), g1 = tanhf_(cg.y + ag.y + bg2.y);
        float o0 = sigmoidf_(co.x + ao.x + bo2.x), o1 = sigmoidf_(co.y + ao.y + bo2.y);
        cst0 = f0 * cst0 + i0 * g0;
        cst1 = f1 * cst1 + i1 * g1;
        float h0 = o0 * tanhf_(cst0);
        float h1 = o1 * tanhf_(cst1);
        u32t hw = (u32t)f2b(h0) | ((u32t)f2b(h1) << 16);
        u32t* dst = (u32t*)h_all +
                    (((size_t)(t + 1) * BATCH + bgr * 32 + grow) * HDIM + hg * 32 + ghl) / 2;
        llc_store_u32(dst, hw);
      }
      asm volatile("s_waitcnt vmcnt(0)" ::: "memory");  // own h stores at LLC
      __syncthreads();                                  // => all threads' h at LLC
      if (tid < 8) llc_store_i32(flags + tid * REP_STRIDE + p, t + 1);
      // --- x pipeline in the publish shadow ---
      if (t + 1 < S_LEN) {
        stx();  // x(t+1) regs -> LDS
        __syncthreads();
        f32x16 z = {};
        acc = z;
#pragma unroll
        for (int kk = 0; kk < 8; ++kk) {
          bf16x8 a = *(const bf16x8*)(axrow + kh * 128 + kk * 16 + ksub);
          acc = __builtin_amdgcn_mfma_f32_32x32x16_bf16(a, bfx[kk], acc, 0, 0, 0);
        }
        ldx((t + 2 < S_LEN) ? t + 2 : 0);  // issue x(t+2) loads (2 steps of slack)
      }
    }
  } else {
    // ===== consumer: 512 threads; all stage, waves 0-3 compute =====
    const int q = blockIdx.x - NPROD;
    short* hlds = (short*)smem;  // [64][LDH]
    int* rep = flags + (blockIdx.x & 7) * REP_STRIDE;
    for (int t = q; t < S_LEN; t += NCONS) {
      if (wave == 0) {
        for (;;) {
          int v = (lane < NPROD) ? llc_load_i32(rep + lane) : 0x7fffffff;
          if (__all(v >= t + 1)) break;
          __builtin_amdgcn_s_sleep(16);
        }
      }
      __syncthreads();
      const u64* hs = (const u64*)h_all + (size_t)(t + 1) * BATCH * (HDIM / 4);
      for (int i = tid; i < 8192; i += 512) {
        int r = i >> 7, cc = i & 127;
        *(u64*)&hlds[r * LDH + cc * 4] = llc_load_u64(hs + i);
      }
      __syncthreads();
      f32x4 acc[32];
      if (wave < 4) {
        const int r0 = wave * 16;
        const short* abase = &hlds[(r0 + (lane & 15)) * LDH + (lane >> 4) * 8];
        const short* bbase = (const short*)wh2o_bf + (size_t)(lane & 15) * HDIM + (lane >> 4) * 8;
        f32x4 zero = {0.f, 0.f, 0.f, 0.f};
#pragma unroll
        for (int n = 0; n < 32; ++n) acc[n] = zero;
        for (int kk = 0; kk < 16; ++kk) {
          bf16x8 a = *(const bf16x8*)(abase + kk * 32);
#pragma unroll
          for (int n = 0; n < 32; ++n) {
            bf16x8 b = *(const bf16x8*)(bbase + (size_t)n * 16 * HDIM + kk * 32);
            acc[n] = __builtin_amdgcn_mfma_f32_16x16x32_bf16(a, b, acc[n], 0, 0, 0);
          }
        }
      }
      __syncthreads();  // hlds consumption complete
      if (wave < 4) {
        const int r0 = wave * 16;
        float mx[4] = {-3.0e38f, -3.0e38f, -3.0e38f, -3.0e38f};
#pragma unroll
        for (int n = 0; n < 32; ++n) {
          float bn = bh2o[n * 16 + (lane & 15)];
#pragma unroll
          for (int j = 0; j < 4; ++j) {
            acc[n][j] += bn;
            mx[j] = fmaxf(mx[j], acc[n][j]);
          }
        }
#pragma unroll
        for (int j = 0; j < 4; ++j) {
          mx[j] = fmaxf(mx[j], __shfl_xor(mx[j], 1));
          mx[j] = fmaxf(mx[j], __shfl_xor(mx[j], 2));
          mx[j] = fmaxf(mx[j], __shfl_xor(mx[j], 4));
          mx[j] = fmaxf(mx[j], __shfl_xor(mx[j], 8));
        }
        float sm[4] = {0.f, 0.f, 0.f, 0.f};
#pragma unroll
        for (int n = 0; n < 32; ++n) {
#pragma unroll
          for (int j = 0; j < 4; ++j) sm[j] += __expf(acc[n][j] - mx[j]);
        }
#pragma unroll
        for (int j = 0; j < 4; ++j) {
          sm[j] += __shfl_xor(sm[j], 1);
          sm[j] += __shfl_xor(sm[j], 2);
          sm[j] += __shfl_xor(sm[j], 4);
          sm[j] += __shfl_xor(sm[j], 8);
        }
        float ls[4];
#pragma unroll
        for (int j = 0; j < 4; ++j) ls[j] = mx[j] + __logf(sm[j]);
        float* ob = out + (size_t)t * BATCH * ODIM;
#pragma unroll
        for (int n = 0; n < 32; ++n) {
#pragma unroll
          for (int j = 0; j < 4; ++j) {
            int row = r0 + (lane >> 4) * 4 + j;
            ob[(size_t)row * ODIM + n * 16 + (lane & 15)] = acc[n][j] - ls[j];
          }
        }
      }
    }
  }
}

extern "C" void kernel_launch(void* const* d_in, const int* in_sizes, int n_in,
                              void* d_out, int out_size, void* d_ws, size_t ws_size,
                              hipStream_t stream) {
  const float* x = (const float*)d_in[0];
  const float* Wi = (const float*)d_in[1];
  const float* bi = (const float*)d_in[2];
  const float* Wf = (const float*)d_in[3];
  const float* bf = (const float*)d_in[4];
  const float* Wg = (const float*)d_in[5];
  const float* bg = (const float*)d_in[6];
  const float* Wo = (const float*)d_in[7];
  const float* bo = (const float*)d_in[8];
  const float* Wh2o = (const float*)d_in[9];
  const float* bh2o = (const float*)d_in[10];

  char* ws = (char*)d_ws;
  int* flags = (int*)ws;
  __hip_bfloat16* h_all = (__hip_bfloat16*)(ws + 16384);
  size_t h_all_bytes = (size_t)(S_LEN + 1) * BATCH * HDIM * 2;
  __hip_bfloat16* wh2o_bf = (__hip_bfloat16*)(ws + 16384 + h_all_bytes);
  size_t needed = 16384 + h_all_bytes + (size_t)ODIM * HDIM * 2;
  if (ws_size < needed || n_in < 11) return;

  hipFuncSetAttribute((const void*)lstm_persist,
                      hipFuncAttributeMaxDynamicSharedMemorySize, SMEM_BYTES);

  lstm_init<<<1024, 256, 0, stream>>>(Wh2o, wh2o_bf, h_all, flags);
  lstm_persist<<<NBLK, 512, SMEM_BYTES, stream>>>(x, Wi, bi, Wf, bf, Wg, bg, Wo, bo,
                                                  wh2o_bf, bh2o, h_all, flags,
                                                  (float*)d_out);
}

// Round 6
// 11464.093 us; speedup vs baseline: 1.7879x; 1.7348x over previous
//
#include <hip/hip_runtime.h>
#include <hip/hip_bf16.h>

typedef __attribute__((ext_vector_type(8))) short bf16x8;
typedef __attribute__((ext_vector_type(4))) float f32x4;
typedef unsigned int u32t;

#define S_LEN 2048
#define BATCH 64
#define IDIM 256
#define HDIM 512
#define KDIM 768
#define ODIM 512
#define NGRP 4        // 4 XCD-local groups x 16 batch rows
#define NSLOT 32      // blocks per group (one per CU of the XCD)
#define LDK 792       // comb row stride (shorts): 1584B rows, 16B aligned, uniform LDS quads
#define FLAG_PAD 16   // ints per flag slot (64B line each)
#define POLL_CAP 10000

// producer LDS map (bytes)
#define OFF_PRE (16 * LDK * 2)             // comb [16][LDK] bf16 = 25344
#define OFF_BIAS (OFF_PRE + 2 * 4 * 16 * 17 * 4)  // pre [2][4][16][17] f32 = 8704 -> 34048
#define SMEM_BYTES 98304  // request 96KB to force exactly 1 block/CU (placement proof)

__device__ __forceinline__ unsigned short f2b(float f) {
  __hip_bfloat16 h = __float2bfloat16(f);
  return __builtin_bit_cast(unsigned short, h);
}
__device__ __forceinline__ float sigmoidf_(float x) { return 1.0f / (1.0f + __expf(-x)); }
__device__ __forceinline__ float tanhf_(float x) { return 1.0f - 2.0f / (1.0f + __expf(2.0f * x)); }

__device__ __forceinline__ bf16x8 cvt8(float4 v0, float4 v1) {
  bf16x8 b;
  b[0] = (short)f2b(v0.x); b[1] = (short)f2b(v0.y);
  b[2] = (short)f2b(v0.z); b[3] = (short)f2b(v0.w);
  b[4] = (short)f2b(v1.x); b[5] = (short)f2b(v1.y);
  b[6] = (short)f2b(v1.z); b[7] = (short)f2b(v1.w);
  return b;
}

// Guaranteed-fresh read of a flag: atomics execute at the XCD L2 (L0 has no RMW
// path), so this can never be served by a stale L0 line. The opaque addend stops
// LLVM from strength-reducing fetch_add(p,0) into a cacheable load.
__device__ __forceinline__ int l2_flag_read(int* p) {
  int z = 0;
  asm volatile("" : "+v"(z));
  return __hip_atomic_fetch_add(p, z, __ATOMIC_RELAXED, __HIP_MEMORY_SCOPE_WORKGROUP);
}

__global__ void lstm_init(const float* __restrict__ wh2o,
                          __hip_bfloat16* __restrict__ wh2o_bf,
                          __hip_bfloat16* __restrict__ h_all,
                          int* __restrict__ ctrl) {
  int idx = blockIdx.x * 256 + threadIdx.x;
  if (idx < ODIM * HDIM) wh2o_bf[idx] = __float2bfloat16(wh2o[idx]);
  if (idx < BATCH * HDIM) h_all[idx] = __float2bfloat16(0.0f);  // h(0) = 0
  if (idx < 4096) ctrl[idx] = 0;                                 // cnt + flags
}

// ===== persistent recurrence: 4 XCD-local groups, no cross-XCD traffic =====
__global__ __launch_bounds__(512) void lstm_recur(
    const float* __restrict__ x,
    const float* __restrict__ Wi, const float* __restrict__ bi,
    const float* __restrict__ Wf, const float* __restrict__ bfp,
    const float* __restrict__ Wg, const float* __restrict__ bgp,
    const float* __restrict__ Wo, const float* __restrict__ bop,
    __hip_bfloat16* __restrict__ h_all, int* __restrict__ flags,
    int* __restrict__ cnt) {
  extern __shared__ char smem[];
  __shared__ int sel[2];
  const int tid = threadIdx.x;
  const int lane = tid & 63;
  const int wave = tid >> 6;

  if (tid == 0) {
    unsigned xcd;
    asm("s_getreg_b32 %0, hwreg(HW_REG_XCC_ID)" : "=s"(xcd));
    sel[0] = (int)(xcd & 7);
    sel[1] = atomicAdd(&cnt[(xcd & 7) * 16], 1);  // device-scope, one-time
  }
  __syncthreads();
  const int g = sel[0];  // group = physical XCD
  const int s = sel[1];  // slot within group = 16 h-cols owned
  if (g >= NGRP || s >= NSLOT) return;  // XCDs 4-7 idle

  short* comb = (short*)smem;               // [16][LDK] bf16: x(256) | h(512)
  float* pre = (float*)(smem + OFF_PRE);    // [2][4][16][17] partial preacts
  float* blds = (float*)(smem + OFF_BIAS);  // [4][16]

  const int ct = wave & 3;   // gate
  const int kh = wave >> 2;  // K-half (384 each: x128 + h256)
  const int rc16 = lane & 15;          // A-row / B-col selector
  const int ksub = (lane >> 4) * 8;    // K sub-offset

  // --- prologue: weight fragments fp32 -> bf16 registers ---
  const float* wsrc = (ct == 0) ? Wi : (ct == 1) ? Wf : (ct == 2) ? Wg : Wo;
  const float* wrow = wsrc + (size_t)(s * 16 + rc16) * KDIM;
  bf16x8 bfx[4], bfh[8];
#pragma unroll
  for (int kk = 0; kk < 4; ++kk) {
    int k0 = kh * 128 + kk * 32 + ksub;
    bfx[kk] = cvt8(*(const float4*)(wrow + k0), *(const float4*)(wrow + k0 + 4));
  }
#pragma unroll
  for (int kk = 0; kk < 8; ++kk) {
    int k0 = IDIM + kh * 256 + kk * 32 + ksub;
    bfh[kk] = cvt8(*(const float4*)(wrow + k0), *(const float4*)(wrow + k0 + 4));
  }
  if (tid < 64) {
    int gate = tid >> 4;
    const float* bsrc = (gate == 0) ? bi : (gate == 1) ? bfp : (gate == 2) ? bgp : bop;
    blds[tid] = bsrc[s * 16 + (tid & 15)];
  }

  // x pipeline: 2-step register lookahead
  float4 rx[2];
  auto ldx = [&](int t) {
    const float4* xs = (const float4*)(x + ((size_t)t * BATCH + g * 16) * IDIM);
    rx[0] = xs[tid];
    rx[1] = xs[tid + 512];
  };
  auto stx = [&]() {
#pragma unroll
    for (int j = 0; j < 2; ++j) {
      int i = tid + j * 512;
      int r = i >> 6, k4 = i & 63;
      float4 v = rx[j];
      ushort4 u;
      u.x = f2b(v.x); u.y = f2b(v.y); u.z = f2b(v.z); u.w = f2b(v.w);
      *(ushort4*)&comb[r * LDK + k4 * 4] = u;
    }
  };

  const short* acx = &comb[rc16 * LDK + kh * 128 + ksub];
  const short* ach = &comb[rc16 * LDK + IDIM + kh * 256 + ksub];

  // bootstrap: x(0) -> LDS -> acc ; x(1) -> regs
  ldx(0);
  stx();
  __syncthreads();
  f32x4 acc = {}, acc2 = {};
  acc = __builtin_amdgcn_mfma_f32_16x16x32_bf16(*(const bf16x8*)(acx + 0), bfx[0], acc, 0, 0, 0);
  acc2 = __builtin_amdgcn_mfma_f32_16x16x32_bf16(*(const bf16x8*)(acx + 32), bfx[1], acc2, 0, 0, 0);
  acc = __builtin_amdgcn_mfma_f32_16x16x32_bf16(*(const bf16x8*)(acx + 64), bfx[2], acc, 0, 0, 0);
  acc2 = __builtin_amdgcn_mfma_f32_16x16x32_bf16(*(const bf16x8*)(acx + 96), bfx[3], acc2, 0, 0, 0);
  ldx(1);

  float cst = 0.0f;                    // c state (tid<256: one (row,col) pair)
  const int gm = tid >> 4;             // gate row 0..15 (within group's 16)
  const int gn = tid & 15;             // gate h-col 0..15 (within slot's 16)
  int* myflag = flags + (g * NSLOT + s) * FLAG_PAD;
  int* gflags = flags + g * NSLOT * FLAG_PAD;

  for (int t = 0; t < S_LEN; ++t) {
    // --- 1. wave0 polls all 32 group flags at the XCD L2 (capped: no hang) ---
    if (wave == 0) {
      for (int it = 0; it < POLL_CAP; ++it) {
        int v = (lane < NSLOT) ? l2_flag_read(gflags + lane * FLAG_PAD) : 0x7fffffff;
        if (__all(v >= t)) break;
        __builtin_amdgcn_s_sleep(1);
      }
    }
    __syncthreads();
    // --- 2. stage h(t) slab -> LDS. Addresses are new every step (h_all[t]),
    //        so plain cached loads can never hit a stale L0 line. ---
    {
      const short* hs = (const short*)h_all + ((size_t)t * BATCH + g * 16) * HDIM;
      int r = tid >> 5, c16 = tid & 31;
      const short* sp = hs + r * HDIM + c16 * 16;
      bf16x8 v0 = *(const bf16x8*)sp;
      bf16x8 v1 = *(const bf16x8*)(sp + 8);
      short* dp = &comb[r * LDK + IDIM + c16 * 16];
      *(bf16x8*)dp = v0;
      *(bf16x8*)(dp + 8) = v1;
    }
    __syncthreads();
    // --- 3. h-part GEMM (2 interleaved chains) ---
#pragma unroll
    for (int kk = 0; kk < 8; kk += 2) {
      acc = __builtin_amdgcn_mfma_f32_16x16x32_bf16(*(const bf16x8*)(ach + kk * 32), bfh[kk],
                                                    acc, 0, 0, 0);
      acc2 = __builtin_amdgcn_mfma_f32_16x16x32_bf16(*(const bf16x8*)(ach + kk * 32 + 32),
                                                     bfh[kk + 1], acc2, 0, 0, 0);
    }
    // --- 4. exchange preacts across waves ---
#pragma unroll
    for (int j = 0; j < 4; ++j) {
      int m = (lane >> 4) * 4 + j;
      pre[((kh * 4 + ct) * 16 + m) * 17 + rc16] = acc[j] + acc2[j];
    }
    __syncthreads();
    // --- 5. gates + state update + publish h(t+1) (plain WT stores -> L2) ---
    if (tid < 256) {
      float pi = blds[gn] + pre[(0 * 16 + gm) * 17 + gn] + pre[(4 * 16 + gm) * 17 + gn];
      float pf = blds[16 + gn] + pre[(1 * 16 + gm) * 17 + gn] + pre[(5 * 16 + gm) * 17 + gn];
      float pg = blds[32 + gn] + pre[(2 * 16 + gm) * 17 + gn] + pre[(6 * 16 + gm) * 17 + gn];
      float po = blds[48 + gn] + pre[(3 * 16 + gm) * 17 + gn] + pre[(7 * 16 + gm) * 17 + gn];
      float ig = sigmoidf_(pi), fg = sigmoidf_(pf), gv = tanhf_(pg), og = sigmoidf_(po);
      cst = fg * cst + ig * gv;
      float hv = og * tanhf_(cst);
      float hv2 = __shfl_xor(hv, 1);
      if ((gn & 1) == 0) {
        u32t hw = (u32t)f2b(hv) | ((u32t)f2b(hv2) << 16);
        u32t* dst = (u32t*)((short*)h_all +
                            ((size_t)(t + 1) * BATCH + g * 16 + gm) * HDIM + s * 16 + gn);
        *dst = hw;
      }
    }
    asm volatile("s_waitcnt vmcnt(0)" ::: "memory");  // own h stores acked at L2
    __syncthreads();                                  // => whole block's h at L2
    if (tid == 0)
      __hip_atomic_store(myflag, t + 1, __ATOMIC_RELAXED, __HIP_MEMORY_SCOPE_WORKGROUP);
    // --- 6. x pipeline in the publish shadow ---
    if (t + 1 < S_LEN) {
      stx();
      __syncthreads();
      f32x4 z = {};
      acc = z;
      acc2 = z;
      acc = __builtin_amdgcn_mfma_f32_16x16x32_bf16(*(const bf16x8*)(acx + 0), bfx[0], acc, 0, 0, 0);
      acc2 = __builtin_amdgcn_mfma_f32_16x16x32_bf16(*(const bf16x8*)(acx + 32), bfx[1], acc2, 0, 0, 0);
      acc = __builtin_amdgcn_mfma_f32_16x16x32_bf16(*(const bf16x8*)(acx + 64), bfx[2], acc, 0, 0, 0);
      acc2 = __builtin_amdgcn_mfma_f32_16x16x32_bf16(*(const bf16x8*)(acx + 96), bfx[3], acc2, 0, 0, 0);
      ldx((t + 2 < S_LEN) ? t + 2 : S_LEN - 1);
    }
  }
}

// ===== output projection + log-softmax: massively parallel, after the scan =====
__global__ __launch_bounds__(256) void lstm_out(
    const __hip_bfloat16* __restrict__ h_all,
    const __hip_bfloat16* __restrict__ wh2o_bf, const float* __restrict__ bh2o,
    float* __restrict__ out) {
  const int t = blockIdx.x;
  const int tid = threadIdx.x;
  const int lane = tid & 63;
  const int wave = tid >> 6;
  const int r0 = wave * 16;
  const short* abase = (const short*)h_all +
                       ((size_t)(t + 1) * BATCH + r0 + (lane & 15)) * HDIM + (lane >> 4) * 8;
  const short* bbase = (const short*)wh2o_bf + (size_t)(lane & 15) * HDIM + (lane >> 4) * 8;
  f32x4 acc[32];
  f32x4 zero = {0.f, 0.f, 0.f, 0.f};
#pragma unroll
  for (int n = 0; n < 32; ++n) acc[n] = zero;
  for (int kk = 0; kk < 16; ++kk) {
    bf16x8 a = *(const bf16x8*)(abase + kk * 32);
#pragma unroll
    for (int n = 0; n < 32; ++n) {
      bf16x8 b = *(const bf16x8*)(bbase + (size_t)n * 16 * HDIM + kk * 32);
      acc[n] = __builtin_amdgcn_mfma_f32_16x16x32_bf16(a, b, acc[n], 0, 0, 0);
    }
  }
  float mx[4] = {-3.0e38f, -3.0e38f, -3.0e38f, -3.0e38f};
#pragma unroll
  for (int n = 0; n < 32; ++n) {
    float bn = bh2o[n * 16 + (lane & 15)];
#pragma unroll
    for (int j = 0; j < 4; ++j) {
      acc[n][j] += bn;
      mx[j] = fmaxf(mx[j], acc[n][j]);
    }
  }
#pragma unroll
  for (int j = 0; j < 4; ++j) {
    mx[j] = fmaxf(mx[j], __shfl_xor(mx[j], 1));
    mx[j] = fmaxf(mx[j], __shfl_xor(mx[j], 2));
    mx[j] = fmaxf(mx[j], __shfl_xor(mx[j], 4));
    mx[j] = fmaxf(mx[j], __shfl_xor(mx[j], 8));
  }
  float sm[4] = {0.f, 0.f, 0.f, 0.f};
#pragma unroll
  for (int n = 0; n < 32; ++n) {
#pragma unroll
    for (int j = 0; j < 4; ++j) sm[j] += __expf(acc[n][j] - mx[j]);
  }
#pragma unroll
  for (int j = 0; j < 4; ++j) {
    sm[j] += __shfl_xor(sm[j], 1);
    sm[j] += __shfl_xor(sm[j], 2);
    sm[j] += __shfl_xor(sm[j], 4);
    sm[j] += __shfl_xor(sm[j], 8);
  }
  float ls[4];
#pragma unroll
  for (int j = 0; j < 4; ++j) ls[j] = mx[j] + __logf(sm[j]);
  float* ob = out + (size_t)t * BATCH * ODIM;
#pragma unroll
  for (int n = 0; n < 32; ++n) {
#pragma unroll
    for (int j = 0; j < 4; ++j) {
      int row = r0 + (lane >> 4) * 4 + j;
      ob[(size_t)row * ODIM + n * 16 + (lane & 15)] = acc[n][j] - ls[j];
    }
  }
}

extern "C" void kernel_launch(void* const* d_in, const int* in_sizes, int n_in,
                              void* d_out, int out_size, void* d_ws, size_t ws_size,
                              hipStream_t stream) {
  const float* x = (const float*)d_in[0];
  const float* Wi = (const float*)d_in[1];
  const float* bi = (const float*)d_in[2];
  const float* Wf = (const float*)d_in[3];
  const float* bf = (const float*)d_in[4];
  const float* Wg = (const float*)d_in[5];
  const float* bg = (const float*)d_in[6];
  const float* Wo = (const float*)d_in[7];
  const float* bo = (const float*)d_in[8];
  const float* Wh2o = (const float*)d_in[9];
  const float* bh2o = (const float*)d_in[10];

  char* ws = (char*)d_ws;
  int* cnt = (int*)ws;                 // 8 XCD counters, padded
  int* flags = (int*)(ws + 4096);      // [NGRP][NSLOT][FLAG_PAD]
  __hip_bfloat16* h_all = (__hip_bfloat16*)(ws + 16384);  // [S+1][64][512] bf16
  size_t h_all_b = (size_t)(S_LEN + 1) * BATCH * HDIM * 2;
  __hip_bfloat16* wh2o_bf = (__hip_bfloat16*)(ws + 16384 + h_all_b);
  size_t needed = 16384 + h_all_b + (size_t)ODIM * HDIM * 2;
  if (ws_size < needed || n_in < 11) return;

  hipFuncSetAttribute((const void*)lstm_recur,
                      hipFuncAttributeMaxDynamicSharedMemorySize, SMEM_BYTES);

  lstm_init<<<1024, 256, 0, stream>>>(Wh2o, wh2o_bf, h_all, (int*)ws);
  lstm_recur<<<256, 512, SMEM_BYTES, stream>>>(x, Wi, bi, Wf, bf, Wg, bg, Wo, bo,
                                               h_all, flags, cnt);
  lstm_out<<<S_LEN, 256, 0, stream>>>(h_all, wh2o_bf, bh2o, (float*)d_out);
}